// Round 9
// baseline (2908.334 us; speedup 1.0000x reference)
//
#include <hip/hip_runtime.h>

// Neural-ODE RK4, swapped-operand MFMA: z^T = W^T @ h^T.
// R8 proved the memory system clean (VGPR=252, WRITE=ybuf exactly, no spill)
// but latency-bound at 1 wave/SIMD (9.7K cy/eval vs 2.5K structural).
// R9: 64 blocks x 16 rows, 4 waves x 64 cols, 256-reg budget (law:
// budget=1024/waves_per_WG). L0 in LDS (128 KB); L1+L2+L3 STREAMED from a
// packed L2$-resident frag buffer through a 6-deep rolling register pipeline
// (6 slots x 16 VGPRs; MA of batch g runs 6 batches behind its LD -> ~270cy
// of issue covers ~220cy L2 latency). Hot-loop barriers are raw s_barrier
// with lgkmcnt-only drain so weight loads stay in flight across barriers
// (the __syncthreads vmcnt(0) drain would re-expose full latency 12x/eval).
// h-tile [16][256] f16 x2, swizzle byte^=(row&7)<<4. RK4 state fp32 in regs.

#define T_ 128
#define IN_ 32
#define H_ 256

typedef _Float16 half8 __attribute__((ext_vector_type(8)));
typedef _Float16 half4 __attribute__((ext_vector_type(4)));
typedef float f32x4 __attribute__((ext_vector_type(4)));

__device__ __forceinline__ f32x4 mfma16(half8 a, half8 b, f32x4 c) {
    return __builtin_amdgcn_mfma_f32_16x16x32_f16(a, b, c, 0, 0, 0);
}

__device__ __forceinline__ half4 cvt4(f32x4 v) {
    half4 h;
    h[0] = (_Float16)v[0]; h[1] = (_Float16)v[1];
    h[2] = (_Float16)v[2]; h[3] = (_Float16)v[3];
    return h;
}

__device__ __forceinline__ f32x4 lips4(f32x4 v) {
    f32x4 r;
#pragma unroll
    for (int e = 0; e < 4; ++e) {
        float x = v[e];
        r[e] = 0.909f * x * __builtin_amdgcn_rcpf(1.f + __expf(-x));
    }
    return r;
}

// lgkmcnt-only drain + raw barrier: vmem weight prefetch survives the barrier.
#define SYNC() do {                                         \
    asm volatile("s_waitcnt lgkmcnt(0)" ::: "memory");      \
    __builtin_amdgcn_s_barrier();                           \
    __builtin_amdgcn_sched_barrier(0);                      \
} while (0)

// h-tile read: lane (lr,lk) reads row lr, colbyte ks*64+lk*16, phys colbyte
// ^= (lr&7)<<4. pe/po keep every read base + compile-time imm.
#define RDH(KS, BUF) (*(const half8*)(ht + (BUF) + (((KS) & 1) ? (po + ((KS)-1)*64) : (pe + (KS)*64))))
#define RDA(C, KS)   (*(const half8*)(w0b + (C)*8192 + (KS)*1024))

#define LOADB(BUF) do { b0=RDH(0,BUF); b1=RDH(1,BUF); b2=RDH(2,BUF); b3=RDH(3,BUF); \
                        b4=RDH(4,BUF); b5=RDH(5,BUF); b6=RDH(6,BUF); b7=RDH(7,BUF); } while (0)

#define L0_KS(KS, BK) do { \
    half8 a0_=RDA(0,KS), a1_=RDA(1,KS), a2_=RDA(2,KS), a3_=RDA(3,KS); \
    acc0=mfma16(a0_,BK,acc0); acc1=mfma16(a1_,BK,acc1); \
    acc2=mfma16(a2_,BK,acc2); acc3=mfma16(a3_,BK,acc3); } while (0)
#define LAYER_L0 do { L0_KS(0,b0); L0_KS(1,b1); L0_KS(2,b2); L0_KS(3,b3); \
                      L0_KS(4,b4); L0_KS(5,b5); L0_KS(6,b6); L0_KS(7,b7); } while (0)

// ---- streamed layers: wave-contiguous pack; batch g (0..23) at wpb+g*4096.
#define LDB(A,B,C,D,G) do { \
    A = *(const half8*)(wpb + (G)*4096);        \
    B = *(const half8*)(wpb + (G)*4096 + 1024); \
    C = *(const half8*)(wpb + (G)*4096 + 2048); \
    D = *(const half8*)(wpb + (G)*4096 + 3072); } while (0)

#define MAB(A,B,C,D, ACC, B0,B1,B2,B3) do { \
    ACC = mfma16(A, B0, ACC); ACC = mfma16(B, B1, ACC); \
    ACC = mfma16(C, B2, ACC); ACC = mfma16(D, B3, ACC); } while (0)

// slot(g) = g%6; after MA of batch g, reload slot with batch (g+6)%24.
#define STREAM_L1 do { \
    MAB(s0a,s0b,s0c,s0d, acc0, b0,b1,b2,b3); LDB(s0a,s0b,s0c,s0d, 6); \
    MAB(s1a,s1b,s1c,s1d, acc0, b4,b5,b6,b7); LDB(s1a,s1b,s1c,s1d, 7); \
    MAB(s2a,s2b,s2c,s2d, acc1, b0,b1,b2,b3); LDB(s2a,s2b,s2c,s2d, 8); \
    MAB(s3a,s3b,s3c,s3d, acc1, b4,b5,b6,b7); LDB(s3a,s3b,s3c,s3d, 9); \
    MAB(s4a,s4b,s4c,s4d, acc2, b0,b1,b2,b3); LDB(s4a,s4b,s4c,s4d,10); \
    MAB(s5a,s5b,s5c,s5d, acc2, b4,b5,b6,b7); LDB(s5a,s5b,s5c,s5d,11); \
    MAB(s0a,s0b,s0c,s0d, acc3, b0,b1,b2,b3); LDB(s0a,s0b,s0c,s0d,12); \
    MAB(s1a,s1b,s1c,s1d, acc3, b4,b5,b6,b7); LDB(s1a,s1b,s1c,s1d,13); \
} while (0)

#define STREAM_L2 do { \
    MAB(s2a,s2b,s2c,s2d, acc0, b0,b1,b2,b3); LDB(s2a,s2b,s2c,s2d,14); \
    MAB(s3a,s3b,s3c,s3d, acc0, b4,b5,b6,b7); LDB(s3a,s3b,s3c,s3d,15); \
    MAB(s4a,s4b,s4c,s4d, acc1, b0,b1,b2,b3); LDB(s4a,s4b,s4c,s4d,16); \
    MAB(s5a,s5b,s5c,s5d, acc1, b4,b5,b6,b7); LDB(s5a,s5b,s5c,s5d,17); \
    MAB(s0a,s0b,s0c,s0d, acc2, b0,b1,b2,b3); LDB(s0a,s0b,s0c,s0d,18); \
    MAB(s1a,s1b,s1c,s1d, acc2, b4,b5,b6,b7); LDB(s1a,s1b,s1c,s1d,19); \
    MAB(s2a,s2b,s2c,s2d, acc3, b0,b1,b2,b3); LDB(s2a,s2b,s2c,s2d,20); \
    MAB(s3a,s3b,s3c,s3d, acc3, b4,b5,b6,b7); LDB(s3a,s3b,s3c,s3d,21); \
} while (0)

#define STREAM_L3 do { \
    MAB(s4a,s4b,s4c,s4d, acc0, b0,b1,b2,b3); LDB(s4a,s4b,s4c,s4d,22); \
    MAB(s5a,s5b,s5c,s5d, acc0, b4,b5,b6,b7); LDB(s5a,s5b,s5c,s5d,23); \
    MAB(s0a,s0b,s0c,s0d, acc1, b0,b1,b2,b3); LDB(s0a,s0b,s0c,s0d, 0); \
    MAB(s1a,s1b,s1c,s1d, acc1, b4,b5,b6,b7); LDB(s1a,s1b,s1c,s1d, 1); \
    MAB(s2a,s2b,s2c,s2d, acc2, b0,b1,b2,b3); LDB(s2a,s2b,s2c,s2d, 2); \
    MAB(s3a,s3b,s3c,s3d, acc2, b4,b5,b6,b7); LDB(s3a,s3b,s3c,s3d, 3); \
    MAB(s4a,s4b,s4c,s4d, acc3, b0,b1,b2,b3); LDB(s4a,s4b,s4c,s4d, 4); \
    MAB(s5a,s5b,s5c,s5d, acc3, b4,b5,b6,b7); LDB(s5a,s5b,s5c,s5d, 5); \
} while (0)

#define ACC_INIT(LY) do { \
    acc0 = *(const f32x4*)(bias4 + (LY)*H_ +  0); \
    acc1 = *(const f32x4*)(bias4 + (LY)*H_ + 16); \
    acc2 = *(const f32x4*)(bias4 + (LY)*H_ + 32); \
    acc3 = *(const f32x4*)(bias4 + (LY)*H_ + 48); } while (0)

#define ACT_STORE(BUF) do { \
    *(half4*)(ht + (BUF) + wo0)        = cvt4(lips4(acc0)); \
    *(half4*)(ht + (BUF) + (wo0^32))   = cvt4(lips4(acc1)); \
    *(half4*)(ht + (BUF) + (wo0^64))   = cvt4(lips4(acc2)); \
    *(half4*)(ht + (BUF) + (wo0^96))   = cvt4(lips4(acc3)); } while (0)

#define STORE_Y(BUF, V0, V1, V2, V3) do { \
    *(half4*)(ht + (BUF) + wo0)        = cvt4(V0); \
    *(half4*)(ht + (BUF) + (wo0^32))   = cvt4(V1); \
    *(half4*)(ht + (BUF) + (wo0^64))   = cvt4(V2); \
    *(half4*)(ht + (BUF) + (wo0^96))   = cvt4(V3); } while (0)

// pack Wf[1..3] wave-contiguous: byte = w*98304 + ly01*32768 + f*1024 + lane*16
__global__ __launch_bounds__(256)
void pack_kernel(const float* __restrict__ Wf, _Float16* __restrict__ wpack)
{
    int idx = blockIdx.x * 256 + threadIdx.x;        // 0..24575
    int lane = idx & 63;
    int f5   = (idx >> 6) & 31;                      // frag within layer
    int rest = idx >> 11;                            // 0..11 = w*3 + ly01
    int ly   = rest % 3;                             // 0..2 -> Wf layer ly+1
    int w    = rest / 3;
    int c = f5 >> 3, ks = f5 & 7;
    int col = w*64 + c*16 + (lane & 15);
    int row = ks*32 + (lane >> 4) * 8;
    const float* src = Wf + ((size_t)(ly + 1) * H_ + row) * H_ + col;
    half8 v;
#pragma unroll
    for (int j = 0; j < 8; ++j) v[j] = (_Float16)src[(size_t)j * H_];
    *(half8*)(wpack + (size_t)idx * 8) = v;
}

__global__ __attribute__((amdgpu_flat_work_group_size(256, 256)))
void ncde_kernel(const float* __restrict__ coeffs,
                 const float* __restrict__ times,
                 const float* __restrict__ W_init,
                 const float* __restrict__ b_init,
                 const float* __restrict__ Wf,
                 const float* __restrict__ bfv,
                 const _Float16* __restrict__ wpack,
                 _Float16* __restrict__ ybuf)
{
    extern __shared__ char smem[];
    _Float16* w0   = (_Float16*)smem;                        // 128 KiB L0 A-frags
    char*     ht   = smem + 131072;                          // 2 x 8 KiB swizzled [16][256] f16
    float*    bias = (float*)(smem + 131072 + 16384);        // [4][256] f32
    float*    tlds = (float*)(smem + 131072 + 16384 + 4096); // [128] f32

    const int tid = threadIdx.x;        // 0..255
    const int l   = tid & 63;
    const int w   = tid >> 6;           // wave 0..3, owns cols [w*64, w*64+64)
    const int lr  = l & 15;             // batch row
    const int lk  = l >> 4;             // 0..3
    const int bc  = blockIdx.x;         // 0..63, rows bc*16..bc*16+15

    const int swz  = (lr & 7) << 4;
    const int base = lr*512 + ((lk*16) ^ (swz & 0x30));
    const int sswz = swz & 0x40;
    const int pe   = base + sswz;
    const int po   = base + 64 - sswz;
    const int wo0  = lr*512 + (((w*128) | (lk*8)) ^ swz);
    const char*  w0b   = (const char*)w0 + (size_t)w * 32768 + l * 16;
    const float* bias4 = bias + w*64 + lk*4;
    const char*  wpb   = (const char*)wpack + (size_t)w * 98304 + l * 16;

    // ---------------- prologue ----------------
    for (int i = tid; i < 4 * H_; i += 256) bias[i] = bfv[i];
    if (tid < T_) tlds[tid] = times[tid];

    // stream pipeline slots (96 VGPRs) + prefetch batches 0..5 (L1 first 24KB)
    half8 s0a,s0b,s0c,s0d, s1a,s1b,s1c,s1d, s2a,s2b,s2c,s2d,
          s3a,s3b,s3c,s3d, s4a,s4b,s4c,s4d, s5a,s5b,s5c,s5d;
    LDB(s0a,s0b,s0c,s0d, 0); LDB(s1a,s1b,s1c,s1d, 1); LDB(s2a,s2b,s2c,s2d, 2);
    LDB(s3a,s3b,s3c,s3d, 3); LDB(s4a,s4b,s4c,s4d, 4); LDB(s5a,s5b,s5c,s5d, 5);

    // layer-0 W^T A-frags into LDS: entry e=(ct*8+ks)*64+ln
    for (int e = tid; e < 8192; e += 256) {
        int ct = e >> 9, ks = (e >> 6) & 7, ln = e & 63;
        const float* src = Wf + (size_t)(ks*32 + ((ln >> 4) << 3)) * H_ + ct*16 + (ln & 15);
        half8 v;
#pragma unroll
        for (int j = 0; j < 8; ++j) v[j] = (_Float16)src[(size_t)j * H_];
        *(half8*)(w0 + (size_t)e * 8) = v;
    }

    // y0 = coeffs[:,0,:] @ W_init + b_init  (fp32 VALU, one-time)
    // lane holds y[bc*16+lr][w*64 + c*16 + lk*4 + r]
    f32x4 y0v, y1v, y2v, y3v;
    {
        const float* crow = coeffs + (size_t)(bc*16 + lr) * (T_ * IN_);
#pragma unroll
        for (int c = 0; c < 4; ++c) {
            f32x4 acc;
#pragma unroll
            for (int r = 0; r < 4; ++r) {
                int col = w*64 + c*16 + lk*4 + r;
                float s = b_init[col];
                for (int k = 0; k < IN_; ++k)
                    s += crow[k] * W_init[(size_t)k * H_ + col];
                acc[r] = s;
            }
            if (c == 0) y0v = acc; else if (c == 1) y1v = acc;
            else if (c == 2) y2v = acc; else y3v = acc;
        }
    }

    STORE_Y(0, y0v, y1v, y2v, y3v);
    __syncthreads();
    {   // dump t=0: unswizzle -> linear [16][256] f16, coalesced 32B/thread
        int drow = tid >> 4, dcb = (tid & 15) * 32, dsw = (drow & 7) << 4;
        const char* sp = ht + drow * 512;
        uint4 a = *(const uint4*)(sp + (dcb ^ dsw));
        uint4 bq = *(const uint4*)(sp + ((dcb + 16) ^ dsw));
        char* dst = (char*)ybuf + (size_t)(bc * T_) * 8192 + tid * 32;
        *(uint4*)dst = a; *(uint4*)(dst + 16) = bq;
    }

    half8 b0, b1, b2, b3, b4, b5, b6, b7;

#pragma unroll 1
    for (int st = 0; st < T_ - 1; ++st) {
        float dt = tlds[st + 1] - tlds[st];
        f32x4 ks0v, ks1v, ks2v, ks3v;
#pragma unroll 1
        for (int s = 0; s < 4; ++s) {
            f32x4 acc0, acc1, acc2, acc3;
            ACC_INIT(0); LOADB(0);    LAYER_L0;  ACT_STORE(8192); SYNC();
            ACC_INIT(1); LOADB(8192); STREAM_L1; ACT_STORE(0);    SYNC();
            ACC_INIT(2); LOADB(0);    STREAM_L2; ACT_STORE(8192); SYNC();
            ACC_INIT(3); LOADB(8192); STREAM_L3;   // k = acc (bias folded);
                                                   // slots now hold next eval's L1 b0..5
            if (s == 0)      { ks0v = acc0;       ks1v = acc1;       ks2v = acc2;       ks3v = acc3; }
            else if (s < 3)  { ks0v += 2.f*acc0;  ks1v += 2.f*acc1;  ks2v += 2.f*acc2;  ks3v += 2.f*acc3; }
            else             { ks0v += acc0;      ks1v += acc1;      ks2v += acc2;      ks3v += acc3; }
            if (s < 3) {
                float cy = (s == 2) ? dt : 0.5f * dt;
                STORE_Y(0, y0v + cy*acc0, y1v + cy*acc1, y2v + cy*acc2, y3v + cy*acc3);
            } else {
                float c6 = dt * (1.f / 6.f);
                y0v += c6*ks0v; y1v += c6*ks1v; y2v += c6*ks2v; y3v += c6*ks3v;
                STORE_Y(0, y0v, y1v, y2v, y3v);
            }
            SYNC();
        }
        {   // dump y at t = st+1 (reads only; next write to ht0 is after next SYNC)
            int drow = tid >> 4, dcb = (tid & 15) * 32, dsw = (drow & 7) << 4;
            const char* sp = ht + drow * 512;
            uint4 a = *(const uint4*)(sp + (dcb ^ dsw));
            uint4 bq = *(const uint4*)(sp + ((dcb + 16) ^ dsw));
            char* dst = (char*)ybuf + (size_t)(bc * T_ + st + 1) * 8192 + tid * 32;
            *(uint4*)dst = a; *(uint4*)(dst + 16) = bq;
        }
    }
}

// out^T = Wd^T @ y^T per (16-batch, t) tile. One wave per (bc, 16 t-steps).
__global__ __launch_bounds__(64)
void proj_kernel(const _Float16* __restrict__ ybuf,
                 const float* __restrict__ Wd,   // [H,32]
                 const float* __restrict__ bd,   // [32]
                 float* __restrict__ out)        // [B,T,32]
{
    const int l  = threadIdx.x;
    const int lr = l & 15, lk = l >> 4;
    const int bc = blockIdx.x;
    const int tg = blockIdx.y;

    half8 wd[2][8];
#pragma unroll
    for (int c = 0; c < 2; ++c)
#pragma unroll
        for (int ks = 0; ks < 8; ++ks) {
            const float* src = Wd + (size_t)(ks*32 + lk*8) * 32 + c*16 + lr;
            half8 v;
#pragma unroll
            for (int j = 0; j < 8; ++j) v[j] = (_Float16)src[(size_t)j * 32];
            wd[c][ks] = v;
        }
    f32x4 bd0 = *(const f32x4*)(bd + lk*4);
    f32x4 bd1 = *(const f32x4*)(bd + 16 + lk*4);

    for (int t = tg*16; t < tg*16 + 16; ++t) {
        const _Float16* yt = ybuf + ((size_t)(bc*T_) + t) * 4096;
        f32x4 a0 = f32x4{0.f,0.f,0.f,0.f}, a1 = f32x4{0.f,0.f,0.f,0.f};
#pragma unroll
        for (int ks = 0; ks < 8; ++ks) {
            half8 b = *(const half8*)(yt + lr*256 + ks*32 + lk*8);
            a0 = mfma16(wd[0][ks], b, a0);
            a1 = mfma16(wd[1][ks], b, a1);
        }
        float* op = out + ((size_t)(bc*16 + lr) * T_ + t) * 32;
        *(f32x4*)(op + lk*4)      = a0 + bd0;
        *(f32x4*)(op + 16 + lk*4) = a1 + bd1;
    }
}

extern "C" void kernel_launch(void* const* d_in, const int* in_sizes, int n_in,
                              void* d_out, int out_size, void* d_ws, size_t ws_size,
                              hipStream_t stream) {
    const float* coeffs = (const float*)d_in[0];
    const float* times  = (const float*)d_in[1];
    const float* W_init = (const float*)d_in[2];
    const float* b_init = (const float*)d_in[3];
    const float* Wf     = (const float*)d_in[4];
    const float* bfv    = (const float*)d_in[5];
    const float* Wd     = (const float*)d_in[6];
    const float* bd     = (const float*)d_in[7];
    _Float16* wpack = (_Float16*)d_ws;                       // 384 KiB packed L1-L3 frags
    _Float16* ybuf  = (_Float16*)((char*)d_ws + 524288);     // 64 MiB
    float* out = (float*)d_out;

    hipLaunchKernelGGL(pack_kernel, dim3(96), dim3(256), 0, stream, Wf, wpack);

    const size_t lds_bytes = 131072 + 16384 + 4096 + 512;    // 152,064 B <= 160 KiB
    hipLaunchKernelGGL(ncde_kernel, dim3(64), dim3(256), lds_bytes, stream,
                       coeffs, times, W_init, b_init, Wf, bfv, wpack, ybuf);
    hipLaunchKernelGGL(proj_kernel, dim3(64, 8), dim3(64), 0, stream,
                       ybuf, Wd, bd, out);
}